// Round 2
// baseline (1454.698 us; speedup 1.0000x reference)
//
#include <hip/hip_runtime.h>

// ---------------------------------------------------------------------------
// SGFormer forward, MI355X/gfx950.
// I/O dtype: FLOAT32 (reference declares jnp.float32; round-1 NaN was f32
// buffers read as bf16 — low halves decode as bf16 NaN 1/256 of the time).
// Internal: h/q/k/v stored bf16 (halves bandwidth), MFMA bf16, f32 accum.
// Math: with s = 1/(||q||_F * ||k||_F):
//   attn = (q @ (k^T v) * s + N*v) / (q . (sum_k) * s + N)
// so we compute raw KV = k^T v [256x256] and ksum [256], then fold s.
// Note N*v dominates the kvs term by ~1e5, so bf16 KV path is precision-safe.
// ---------------------------------------------------------------------------

typedef __attribute__((ext_vector_type(8))) short short8;
typedef __attribute__((ext_vector_type(4))) float floatx4;

__device__ __forceinline__ float bf2f(short u) {
    union { unsigned int i; float f; } v;
    v.i = ((unsigned int)(unsigned short)u) << 16;
    return v.f;
}
__device__ __forceinline__ short f2bf(float f) {
    union { float f; unsigned int i; } v; v.f = f;
    unsigned int b = v.i + 0x7fffu + ((v.i >> 16) & 1u);  // RNE
    return (short)(b >> 16);
}

#define HID 256
#define EPSLN 1e-5f

// ---------------------------------------------------------------------------
// Panel GEMM: C[M,256] = A[M,K] @ B[K,256]  (B transposed bf16: BT[256][K])
// A is f32 (AF32=true, converted inline) or internal bf16.
// Block: 256 threads = 4 waves; tile 32 rows x 256 cols (full panel width so
// LayerNorm fuses). Wave w owns cols [64w,64w+64): 2(m) x 4(n) MFMA frags.
// EPI=0: bias + bf16 store, optional Frobenius sumsq + column-sum atomics
// EPI=1: bias + LayerNorm + ReLU  (stage 0)
// EPI=2: attention epilogue: acc = q@(KV*s); num=acc+N*v; den=q.ksum_s+N;
//        h = 0.5*num/den + 0.5*prev; LayerNorm. In-place over Prev is safe:
//        each block touches only its own 32 rows.
// ---------------------------------------------------------------------------
template <int EPI, bool AF32>
__global__ __launch_bounds__(256)
void gemm_panel(const void* __restrict__ Av, const short* __restrict__ BT,
                short* __restrict__ C, int K,
                const float* __restrict__ bias,
                float* __restrict__ sumsq, float* __restrict__ colsum,
                const float* __restrict__ lng, const float* __restrict__ lnb,
                const short* __restrict__ Vmat, const short* __restrict__ Prev,
                const float* __restrict__ ksum_s, float Nf)
{
    const int tid  = threadIdx.x;
    const int wave = tid >> 6, lane = tid & 63;
    const int quad = lane >> 4, l15 = lane & 15;
    const int row0 = blockIdx.x * 32;
    const int nb   = wave * 64;

    floatx4 acc[2][4];
#pragma unroll
    for (int m = 0; m < 2; m++)
#pragma unroll
        for (int n = 0; n < 4; n++) acc[m][n] = (floatx4)0.0f;

    const float* Af = (const float*)Av + (size_t)(row0 + l15) * K + quad * 8;
    const short* Ab = (const short*)Av + (size_t)(row0 + l15) * K + quad * 8;

    for (int kk = 0; kk < K; kk += 32) {
        short8 a0, a1;
        if constexpr (AF32) {
            floatx4 x0 = *(const floatx4*)(Af + kk);
            floatx4 x1 = *(const floatx4*)(Af + kk + 4);
            floatx4 y0 = *(const floatx4*)(Af + kk + (size_t)16 * K);
            floatx4 y1 = *(const floatx4*)(Af + kk + (size_t)16 * K + 4);
#pragma unroll
            for (int i = 0; i < 4; i++) {
                a0[i] = f2bf(x0[i]); a0[4 + i] = f2bf(x1[i]);
                a1[i] = f2bf(y0[i]); a1[4 + i] = f2bf(y1[i]);
            }
        } else {
            a0 = *(const short8*)(Ab + kk);
            a1 = *(const short8*)(Ab + kk + (size_t)16 * K);
        }
#pragma unroll
        for (int n = 0; n < 4; n++) {
            short8 b = *(const short8*)(BT + (size_t)(nb + n * 16 + l15) * K + kk + quad * 8);
            acc[0][n] = __builtin_amdgcn_mfma_f32_16x16x32_bf16(a0, b, acc[0][n], 0, 0, 0);
            acc[1][n] = __builtin_amdgcn_mfma_f32_16x16x32_bf16(a1, b, acc[1][n], 0, 0, 0);
        }
    }

    float bn[4];
#pragma unroll
    for (int n = 0; n < 4; n++) bn[n] = bias ? bias[nb + n * 16 + l15] : 0.0f;

    if constexpr (EPI == 0) {
        float ssq = 0.f;
        float csum[4] = {0.f, 0.f, 0.f, 0.f};
#pragma unroll
        for (int m = 0; m < 2; m++)
#pragma unroll
            for (int n = 0; n < 4; n++)
#pragma unroll
                for (int r = 0; r < 4; r++) {
                    float val = acc[m][n][r] + bn[n];
                    int row = row0 + m * 16 + quad * 4 + r;
                    int col = nb + n * 16 + l15;
                    C[(size_t)row * HID + col] = f2bf(val);
                    ssq += val * val;
                    csum[n] += val;
                }
        if (sumsq) {  // Frobenius sum-of-squares (f32, pre-bf16-rounding)
#pragma unroll
            for (int off = 32; off; off >>= 1) ssq += __shfl_down(ssq, off);
            __shared__ float sblk;
            if (tid == 0) sblk = 0.f;
            __syncthreads();
            if (lane == 0) atomicAdd(&sblk, ssq);
            __syncthreads();
            if (tid == 0) atomicAdd(sumsq, sblk);
        }
        if (colsum) {  // per-column sum (for ksum)
#pragma unroll
            for (int n = 0; n < 4; n++) {
                float v = csum[n];
                v += __shfl_xor(v, 16);
                v += __shfl_xor(v, 32);
                if (quad == 0) atomicAdd(&colsum[nb + n * 16 + l15], v);
            }
        }
    } else {
        __shared__ float tile[32][260];  // +4 pad breaks pow2 bank stride
        __shared__ float red0[32][8];
        __shared__ float red1[32][8];
        __shared__ float rowa[32], rowb[32];
#pragma unroll
        for (int m = 0; m < 2; m++)
#pragma unroll
            for (int n = 0; n < 4; n++)
#pragma unroll
                for (int r = 0; r < 4; r++)
                    tile[m * 16 + quad * 4 + r][nb + n * 16 + l15] = acc[m][n][r] + bn[n];
        __syncthreads();

        const int rr = tid >> 3, sg = tid & 7, seg = sg * 32;

        if constexpr (EPI == 2) {
            // denominator: q_row . ksum_s + N  (8 threads cooperate per row)
            const short* qrow = (const short*)Av + (size_t)(row0 + rr) * HID;
            float dp = 0.f;
            for (int c = seg; c < seg + 32; c++) dp += bf2f(qrow[c]) * ksum_s[c];
            red0[rr][sg] = dp;
            __syncthreads();
            if (tid < 32) {
                float d = Nf;
                for (int i = 0; i < 8; i++) d += red0[tid][i];
                rowa[tid] = d;
            }
            __syncthreads();
            float den = rowa[rr];
            const short* vrow = Vmat + (size_t)(row0 + rr) * HID;
            const short* prow = Prev + (size_t)(row0 + rr) * HID;
            float s = 0.f, s2 = 0.f;
            for (int c = seg; c < seg + 32; c++) {
                float num = tile[rr][c] + Nf * bf2f(vrow[c]);
                float hn  = 0.5f * (num / den) + 0.5f * bf2f(prow[c]);
                tile[rr][c] = hn;
                s += hn; s2 += hn * hn;
            }
            red0[rr][sg] = s; red1[rr][sg] = s2;
            __syncthreads();
        } else {
            float s = 0.f, s2 = 0.f;
            for (int c = seg; c < seg + 32; c++) { float x = tile[rr][c]; s += x; s2 += x * x; }
            red0[rr][sg] = s; red1[rr][sg] = s2;
            __syncthreads();
        }

        if (tid < 32) {  // per-row mean / rstd
            float s = 0.f, s2 = 0.f;
            for (int i = 0; i < 8; i++) { s += red0[tid][i]; s2 += red1[tid][i]; }
            float mean = s * (1.0f / 256.0f);
            float var  = s2 * (1.0f / 256.0f) - mean * mean;
            rowa[tid] = mean;
            rowb[tid] = rsqrtf(var + EPSLN);
        }
        __syncthreads();
        float mean = rowa[rr], rstd = rowb[rr];
        short* crow = C + (size_t)(row0 + rr) * HID;
        for (int c = seg; c < seg + 32; c += 8) {
            short8 outv;
#pragma unroll
            for (int i = 0; i < 8; i++) {
                float x = (tile[rr][c + i] - mean) * rstd;
                x = x * lng[c + i] + lnb[c + i];
                if constexpr (EPI == 1) x = fmaxf(x, 0.f);
                outv[i] = f2bf(x);
            }
            *(short8*)(crow + c) = outv;
        }
    }
}

// ---------------------------------------------------------------------------
// KV = k^T @ v  [256x256] f32, split-K over grid.z, MFMA via LDS transpose.
// Block tile 128(m) x 128(n), grid (2,2,CH). Both A (=k^T) and B (=v) frags
// want 8 contiguous K-elements/lane, so we stage both tiles TRANSPOSED in LDS
// ([col][row], padded stride 40) -> single ds_read_b128 per fragment.
// ---------------------------------------------------------------------------
__global__ __launch_bounds__(256)
void kv_kernel(const short* __restrict__ k, const short* __restrict__ v,
               float* __restrict__ KV, int M)
{
    __shared__ short ksT[128][40];
    __shared__ short vsT[128][40];
    const int t = threadIdx.x, wave = t >> 6, lane = t & 63;
    const int quad = lane >> 4, l15 = lane & 15;
    const int mb = blockIdx.x * 128, nbb = blockIdx.y * 128;
    const int chunk = (M + (int)gridDim.z - 1) / (int)gridDim.z;
    const int rbeg = blockIdx.z * chunk;
    const int rend = min(M, rbeg + chunk);

    floatx4 acc[2][8];
#pragma unroll
    for (int m = 0; m < 2; m++)
#pragma unroll
        for (int j = 0; j < 8; j++) acc[m][j] = (floatx4)0.0f;

    const int lr = t >> 3, c0 = (t & 7) * 16;
    const int wm = wave * 32;

    for (int r0 = rbeg; r0 < rend; r0 += 32) {
        int gr = r0 + lr;
        short8 k0 = (short8)(short)0, k1 = (short8)(short)0;
        short8 v0 = (short8)(short)0, v1 = (short8)(short)0;
        if (gr < rend) {
            const short* kp = k + (size_t)gr * HID + mb + c0;
            const short* vp = v + (size_t)gr * HID + nbb + c0;
            k0 = *(const short8*)kp;  k1 = *(const short8*)(kp + 8);
            v0 = *(const short8*)vp;  v1 = *(const short8*)(vp + 8);
        }
        __syncthreads();  // previous iter's LDS reads complete
#pragma unroll
        for (int i = 0; i < 8; i++) {
            ksT[c0 + i][lr] = k0[i];  ksT[c0 + 8 + i][lr] = k1[i];
            vsT[c0 + i][lr] = v0[i];  vsT[c0 + 8 + i][lr] = v1[i];
        }
        __syncthreads();
        short8 a0 = *(const short8*)&ksT[wm + l15][quad * 8];
        short8 a1 = *(const short8*)&ksT[wm + 16 + l15][quad * 8];
#pragma unroll
        for (int j = 0; j < 8; j++) {
            short8 b = *(const short8*)&vsT[j * 16 + l15][quad * 8];
            acc[0][j] = __builtin_amdgcn_mfma_f32_16x16x32_bf16(a0, b, acc[0][j], 0, 0, 0);
            acc[1][j] = __builtin_amdgcn_mfma_f32_16x16x32_bf16(a1, b, acc[1][j], 0, 0, 0);
        }
    }
#pragma unroll
    for (int mi = 0; mi < 2; mi++)
#pragma unroll
        for (int j = 0; j < 8; j++)
#pragma unroll
            for (int r = 0; r < 4; r++) {
                int m = mb + wm + mi * 16 + quad * 4 + r;
                int n = nbb + j * 16 + l15;
                atomicAdd(&KV[(size_t)m * HID + n], acc[mi][j][r]);
            }
}

// KVt_s[d][m] = KV[m][d] / (||q|| * ||k||);  ksum_s = ksum / (||q||*||k||)
__global__ void scale_kernel(const float* __restrict__ KV, const float* __restrict__ ksum,
                             const float* __restrict__ sq,  // [sumsq_q, sumsq_k]
                             short* __restrict__ KVt, float* __restrict__ ksum_s)
{
    float s = rsqrtf(sq[0]) * rsqrtf(sq[1]);
    int m = blockIdx.x, d = threadIdx.x;
    KVt[(size_t)d * HID + m] = f2bf(KV[(size_t)m * HID + d] * s);
    if (m == 0) ksum_s[d] = ksum[d] * s;
}

// ---------------------------------------------------------------------------
// Final GEMM: Out[M,40] = h[M,256] @ W_out[256,40] + b_out (N padded to 48)
// ---------------------------------------------------------------------------
__global__ __launch_bounds__(256)
void gemm_out(const short* __restrict__ A, const short* __restrict__ BT,
              const float* __restrict__ bias, float* __restrict__ Out, int M)
{
    const int tid = threadIdx.x, wave = tid >> 6, lane = tid & 63;
    const int quad = lane >> 4, l15 = lane & 15;
    const int row0 = blockIdx.x * 128 + wave * 32;
    const int K = 256;
    floatx4 acc[2][3];
#pragma unroll
    for (int m = 0; m < 2; m++)
#pragma unroll
        for (int n = 0; n < 3; n++) acc[m][n] = (floatx4)0.0f;

    int ra0 = min(row0 + l15, M - 1);       // clamp tail reads, discard on store
    int ra1 = min(row0 + 16 + l15, M - 1);
    for (int kk = 0; kk < K; kk += 32) {
        short8 a0 = *(const short8*)(A + (size_t)ra0 * K + kk + quad * 8);
        short8 a1 = *(const short8*)(A + (size_t)ra1 * K + kk + quad * 8);
#pragma unroll
        for (int n = 0; n < 3; n++) {
            int col = n * 16 + l15;
            short8 b = (short8)(short)0;
            if (col < 40) b = *(const short8*)(BT + (size_t)col * K + kk + quad * 8);
            acc[0][n] = __builtin_amdgcn_mfma_f32_16x16x32_bf16(a0, b, acc[0][n], 0, 0, 0);
            acc[1][n] = __builtin_amdgcn_mfma_f32_16x16x32_bf16(a1, b, acc[1][n], 0, 0, 0);
        }
    }
#pragma unroll
    for (int m = 0; m < 2; m++)
#pragma unroll
        for (int n = 0; n < 3; n++)
#pragma unroll
            for (int r = 0; r < 4; r++) {
                int row = row0 + m * 16 + quad * 4 + r;
                int col = n * 16 + l15;
                if (row < M && col < 40)
                    Out[(size_t)row * 40 + col] = acc[m][n][r] + bias[col];
            }
}

// --------------------------- small utility kernels -------------------------
struct TJobs { const float* src[8]; short* dst[8]; int R[8]; int C[8]; };

__global__ void wtrans(TJobs j)  // dst[C][R] = bf16(src[R][C]), 8 jobs
{
    int job = blockIdx.y;
    int R = j.R[job], Cc = j.C[job];
    const float* s = j.src[job];
    short* d = j.dst[job];
    int n = R * Cc;
    for (int idx = blockIdx.x * 256 + threadIdx.x; idx < n; idx += gridDim.x * 256) {
        int r = idx / Cc, c = idx - r * Cc;
        d[(size_t)c * R + r] = f2bf(s[idx]);
    }
}

__global__ void zerof(float* p, int n)
{
    int i = blockIdx.x * 256 + threadIdx.x;
    if (i < n) p[i] = 0.f;
}

// ---------------------------------------------------------------------------
extern "C" void kernel_launch(void* const* d_in, const int* in_sizes, int n_in,
                              void* d_out, int out_size, void* d_ws, size_t ws_size,
                              hipStream_t stream)
{
    const float* x    = (const float*)d_in[0];
    // d_in[1] = edge_index: unused (use_graph=False)
    const float* W_in = (const float*)d_in[2];
    const float* b_in = (const float*)d_in[3];
    const float* ln0g = (const float*)d_in[4];
    const float* ln0b = (const float*)d_in[5];
    const float* Wq0  = (const float*)d_in[6];  const float* bq0 = (const float*)d_in[7];
    const float* Wk0  = (const float*)d_in[8];  const float* bk0 = (const float*)d_in[9];
    const float* Wv0  = (const float*)d_in[10]; const float* bv0 = (const float*)d_in[11];
    const float* ln1g = (const float*)d_in[12]; const float* ln1b = (const float*)d_in[13];
    const float* Wq1  = (const float*)d_in[14]; const float* bq1 = (const float*)d_in[15];
    const float* Wk1  = (const float*)d_in[16]; const float* bk1 = (const float*)d_in[17];
    const float* Wv1  = (const float*)d_in[18]; const float* bv1 = (const float*)d_in[19];
    const float* ln2g = (const float*)d_in[20]; const float* ln2b = (const float*)d_in[21];
    const float* W_out = (const float*)d_in[22]; const float* b_out = (const float*)d_in[23];

    const int M = 100000;
    char* ws = (char*)d_ws;
    size_t off = 0;
    auto alloc = [&](size_t bytes) -> char* {
        char* p = ws + off;
        off += (bytes + 255) & ~(size_t)255;
        return p;
    };
    short* h = (short*)alloc((size_t)M * HID * 2);
    short* q = (short*)alloc((size_t)M * HID * 2);
    short* k = (short*)alloc((size_t)M * HID * 2);
    short* v = (short*)alloc((size_t)M * HID * 2);
    short* WinT  = (short*)alloc((size_t)512 * 256 * 2);
    short* WqT0  = (short*)alloc((size_t)65536 * 2);
    short* WkT0  = (short*)alloc((size_t)65536 * 2);
    short* WvT0  = (short*)alloc((size_t)65536 * 2);
    short* WqT1  = (short*)alloc((size_t)65536 * 2);
    short* WkT1  = (short*)alloc((size_t)65536 * 2);
    short* WvT1  = (short*)alloc((size_t)65536 * 2);
    short* WoutT = (short*)alloc((size_t)40 * 256 * 2);
    // contiguous zero-init region: KV0, KV1, ksum0, ksum1, sq[4]
    float* zbase = (float*)alloc((size_t)(65536 * 2 + 256 * 2 + 4) * 4);
    float* KV0 = zbase;
    float* KV1 = zbase + 65536;
    float* ksum0 = zbase + 131072;
    float* ksum1 = ksum0 + 256;
    float* sq = ksum1 + 256;  // [sq_q0, sq_k0, sq_q1, sq_k1]
    short* KVt0 = (short*)alloc((size_t)65536 * 2);
    short* KVt1 = (short*)alloc((size_t)65536 * 2);
    float* ksum_s0 = (float*)alloc(256 * 4);
    float* ksum_s1 = (float*)alloc(256 * 4);

    const int ZN = 65536 * 2 + 256 * 2 + 4;
    zerof<<<dim3((ZN + 255) / 256), 256, 0, stream>>>(zbase, ZN);

    TJobs tj;
    tj.src[0] = W_in;  tj.dst[0] = WinT;  tj.R[0] = 512; tj.C[0] = 256;
    tj.src[1] = Wq0;   tj.dst[1] = WqT0;  tj.R[1] = 256; tj.C[1] = 256;
    tj.src[2] = Wk0;   tj.dst[2] = WkT0;  tj.R[2] = 256; tj.C[2] = 256;
    tj.src[3] = Wv0;   tj.dst[3] = WvT0;  tj.R[3] = 256; tj.C[3] = 256;
    tj.src[4] = Wq1;   tj.dst[4] = WqT1;  tj.R[4] = 256; tj.C[4] = 256;
    tj.src[5] = Wk1;   tj.dst[5] = WkT1;  tj.R[5] = 256; tj.C[5] = 256;
    tj.src[6] = Wv1;   tj.dst[6] = WvT1;  tj.R[6] = 256; tj.C[6] = 256;
    tj.src[7] = W_out; tj.dst[7] = WoutT; tj.R[7] = 256; tj.C[7] = 40;
    wtrans<<<dim3(512, 8), 256, 0, stream>>>(tj);

    const int GB = M / 32;  // 3125, exact
    const float Nf = (float)M;

    // stage 0: h = relu(LN(x @ W_in + b_in))   (x is f32, converted inline)
    gemm_panel<1, true><<<GB, 256, 0, stream>>>(x, WinT, h, 512, b_in,
                                          nullptr, nullptr, ln0g, ln0b,
                                          nullptr, nullptr, nullptr, 0.f);
    // ---- layer 0 ----
    gemm_panel<0, false><<<GB, 256, 0, stream>>>(h, WqT0, q, 256, bq0, sq + 0, nullptr,
                                          nullptr, nullptr, nullptr, nullptr, nullptr, 0.f);
    gemm_panel<0, false><<<GB, 256, 0, stream>>>(h, WkT0, k, 256, bk0, sq + 1, ksum0,
                                          nullptr, nullptr, nullptr, nullptr, nullptr, 0.f);
    gemm_panel<0, false><<<GB, 256, 0, stream>>>(h, WvT0, v, 256, bv0, nullptr, nullptr,
                                          nullptr, nullptr, nullptr, nullptr, nullptr, 0.f);
    kv_kernel<<<dim3(2, 2, 64), 256, 0, stream>>>(k, v, KV0, M);
    scale_kernel<<<256, 256, 0, stream>>>(KV0, ksum0, sq + 0, KVt0, ksum_s0);
    gemm_panel<2, false><<<GB, 256, 0, stream>>>(q, KVt0, h, 256, nullptr,
                                          nullptr, nullptr, ln1g, ln1b,
                                          v, h, ksum_s0, Nf);
    // ---- layer 1 ----
    gemm_panel<0, false><<<GB, 256, 0, stream>>>(h, WqT1, q, 256, bq1, sq + 2, nullptr,
                                          nullptr, nullptr, nullptr, nullptr, nullptr, 0.f);
    gemm_panel<0, false><<<GB, 256, 0, stream>>>(h, WkT1, k, 256, bk1, sq + 3, ksum1,
                                          nullptr, nullptr, nullptr, nullptr, nullptr, 0.f);
    gemm_panel<0, false><<<GB, 256, 0, stream>>>(h, WvT1, v, 256, bv1, nullptr, nullptr,
                                          nullptr, nullptr, nullptr, nullptr, nullptr, 0.f);
    kv_kernel<<<dim3(2, 2, 64), 256, 0, stream>>>(k, v, KV1, M);
    scale_kernel<<<256, 256, 0, stream>>>(KV1, ksum1, sq + 2, KVt1, ksum_s1);
    gemm_panel<2, false><<<GB, 256, 0, stream>>>(q, KVt1, h, 256, nullptr,
                                          nullptr, nullptr, ln2g, ln2b,
                                          v, h, ksum_s1, Nf);
    // ---- output ----
    gemm_out<<<(M + 127) / 128, 256, 0, stream>>>(h, WoutT, b_out, (float*)d_out, M);
}

// Round 3
// 1298.842 us; speedup vs baseline: 1.1200x; 1.1200x over previous
//
#include <hip/hip_runtime.h>

// ---------------------------------------------------------------------------
// SGFormer forward, MI355X/gfx950.  I/O f32; internal h/q/k/v bf16.
// attn = (q @ (k^T v) * s + N*v) / (q . (sum_k) * s + N),  s = 1/(||q|| ||k||)
// KVt buffer is 272 rows x 256: rows 0..255 = (KV*s)^T, row 256 = ksum*s,
// rows 257..271 = 0.  The attention kernel computes the denominator with one
// extra MFMA n-column (wave 0) instead of a scalar epilogue dot product.
// Panel GEMM: 128 rows x 256 cols/block, A staged in LDS (128-k slabs) via
// global_load_lds w/ XOR swizzle; B (<=140KB) stays L2-resident from global.
// ---------------------------------------------------------------------------

typedef __attribute__((ext_vector_type(8))) short short8;
typedef __attribute__((ext_vector_type(4))) float floatx4;

__device__ __forceinline__ float bf2f(short u) {
    union { unsigned int i; float f; } v;
    v.i = ((unsigned int)(unsigned short)u) << 16;
    return v.f;
}
__device__ __forceinline__ short f2bf(float f) {
    union { float f; unsigned int i; } v; v.f = f;
    unsigned int b = v.i + 0x7fffu + ((v.i >> 16) & 1u);  // RNE
    return (short)(b >> 16);
}

#define HID 256
#define M_ROWS 100000
#define EPSLN 1e-5f
#define TM 128
#define SLAB 128
#define CPR (SLAB / 8)        // 16 chunks (16B) per row-slab
#define NCHUNK (TM * CPR)     // 2048 chunks per A-tile

// ---------------------------------------------------------------------------
// EPI=0: bias + bf16 store + optional Frobenius sumsq + column-sum atomics
// EPI=1: bias + LayerNorm + ReLU (stage 0; AF32 input)
// EPI=2: attention: acc=q@KVt_s (+den col via KVt row 256 on wave 0);
//        h = 0.5*(acc+N*v)/den + 0.5*prev; LayerNorm.  In-place h is safe
//        (block reads/writes only its own 128 rows; A=q is a different buf).
// ---------------------------------------------------------------------------
template <int EPI, bool AF32>
__global__ __launch_bounds__(256)
void gemm_panel(const void* __restrict__ Av, const short* __restrict__ BT,
                short* __restrict__ C, int K,
                const float* __restrict__ bias,
                float* __restrict__ sumsq, float* __restrict__ colsum,
                const float* __restrict__ lng, const float* __restrict__ lnb,
                const short* __restrict__ Vmat, const short* __restrict__ Prev,
                float Nf)
{
    __shared__ short As[NCHUNK * 8];      // 32 KB, XOR-swizzled chunks
    __shared__ float redS[TM][4];
    __shared__ float redQ[TM][4];
    __shared__ float rowm[TM];
    __shared__ float rowr[TM];
    __shared__ float denA[TM];            // EPI2: 1/den per row; EPI0: [0]=scratch

    const int tid  = threadIdx.x;
    const int wave = tid >> 6, lane = tid & 63;
    const int quad = lane >> 4, l15 = lane & 15;
    const int row0 = blockIdx.x * TM;
    const int nb   = wave * 64;

    floatx4 acc[8][4];
#pragma unroll
    for (int m = 0; m < 8; m++)
#pragma unroll
        for (int n = 0; n < 4; n++) acc[m][n] = (floatx4)0.0f;
    floatx4 accd[8];
    if constexpr (EPI == 2) {
#pragma unroll
        for (int m = 0; m < 8; m++) accd[m] = (floatx4)0.0f;
    }

    const float* Af = (const float*)Av;
    const short* Ab = (const short*)Av;

    for (int slab = 0; slab < K; slab += SLAB) {
        __syncthreads();  // prior slab's LDS reads complete before restaging
        if constexpr (AF32) {
            // f32 -> bf16 convert through registers, swizzled ds_write_b128
#pragma unroll
            for (int it = 0; it < NCHUNK / 256; ++it) {
                int J = it * 256 + tid;
                int row = J >> 4, jj = J & 15, c = jj ^ (row & 15);
                int rowg = min(row0 + row, M_ROWS - 1);
                const float* gp = Af + (size_t)rowg * K + slab + c * 8;
                floatx4 x0 = *(const floatx4*)gp;
                floatx4 x1 = *(const floatx4*)(gp + 4);
                short8 s8;
#pragma unroll
                for (int i = 0; i < 4; ++i) { s8[i] = f2bf(x0[i]); s8[i + 4] = f2bf(x1[i]); }
                *(short8*)&As[(size_t)J * 8] = s8;
            }
        } else {
            // async 16B global->LDS; dest is wave-uniform base + lane*16, so
            // the XOR swizzle is baked into the per-lane SOURCE address.
            const int base = wave * (NCHUNK / 4);
#pragma unroll
            for (int it = 0; it < NCHUNK / 256; ++it) {
                int J = base + it * 64 + lane;
                int row = J >> 4, jj = J & 15, c = jj ^ (row & 15);
                int rowg = min(row0 + row, M_ROWS - 1);
                const short* gp = Ab + (size_t)rowg * K + slab + c * 8;
                __builtin_amdgcn_global_load_lds(
                    (const __attribute__((address_space(1))) void*)gp,
                    (__attribute__((address_space(3))) void*)&As[(size_t)(base + it * 64) * 8],
                    16, 0, 0);
            }
        }
        __syncthreads();
#pragma unroll
        for (int ki = 0; ki < SLAB / 32; ++ki) {
            short8 a[8];
#pragma unroll
            for (int m = 0; m < 8; ++m) {
                int row = m * 16 + l15;
                int L = (row << 4) | ((ki * 4 + quad) ^ (row & 15));
                a[m] = *(const short8*)&As[(size_t)L * 8];
            }
#pragma unroll
            for (int n = 0; n < 4; ++n) {
                short8 b = *(const short8*)(BT + (size_t)(nb + n * 16 + l15) * K + slab + ki * 32 + quad * 8);
#pragma unroll
                for (int m = 0; m < 8; ++m)
                    acc[m][n] = __builtin_amdgcn_mfma_f32_16x16x32_bf16(a[m], b, acc[m][n], 0, 0, 0);
            }
            if constexpr (EPI == 2) {
                if (wave == 0) {  // denominator column: KVt rows 256..271
                    short8 bd = *(const short8*)(BT + (size_t)(256 + l15) * K + slab + ki * 32 + quad * 8);
#pragma unroll
                    for (int m = 0; m < 8; ++m)
                        accd[m] = __builtin_amdgcn_mfma_f32_16x16x32_bf16(a[m], bd, accd[m], 0, 0, 0);
                }
            }
        }
    }

    // ------------------------------- epilogues -----------------------------
    if constexpr (EPI == 0) {
        float bn[4];
#pragma unroll
        for (int n = 0; n < 4; n++) bn[n] = bias[nb + n * 16 + l15];
        float ssq = 0.f;
        float csum[4] = {0.f, 0.f, 0.f, 0.f};
#pragma unroll
        for (int m = 0; m < 8; m++)
#pragma unroll
            for (int r = 0; r < 4; r++) {
                int row = row0 + m * 16 + quad * 4 + r;
                if (row < M_ROWS) {
#pragma unroll
                    for (int n = 0; n < 4; n++) {
                        float val = acc[m][n][r] + bn[n];
                        C[(size_t)row * HID + nb + n * 16 + l15] = f2bf(val);
                        ssq += val * val;
                        csum[n] += val;
                    }
                }
            }
        if (sumsq) {
#pragma unroll
            for (int off = 32; off; off >>= 1) ssq += __shfl_down(ssq, off);
            if (tid == 0) denA[0] = 0.f;
            __syncthreads();
            if (lane == 0) atomicAdd(&denA[0], ssq);
            __syncthreads();
            if (tid == 0) atomicAdd(sumsq, denA[0]);
        }
        if (colsum) {
#pragma unroll
            for (int n = 0; n < 4; n++) {
                float vv = csum[n];
                vv += __shfl_xor(vv, 16);
                vv += __shfl_xor(vv, 32);
                if (quad == 0) atomicAdd(&colsum[nb + n * 16 + l15], vv);
            }
        }
    } else {
        if constexpr (EPI == 2) {
            if (wave == 0 && l15 == 0) {
#pragma unroll
                for (int m = 0; m < 8; m++)
#pragma unroll
                    for (int r = 0; r < 4; r++) {
                        int rl = m * 16 + quad * 4 + r;
                        denA[rl] = __builtin_amdgcn_rcpf(accd[m][r] + Nf);
                    }
            }
            __syncthreads();
#pragma unroll
            for (int m = 0; m < 8; m++)
#pragma unroll
                for (int r = 0; r < 4; r++) {
                    int rl = m * 16 + quad * 4 + r;
                    int rowc = min(row0 + rl, M_ROWS - 1);
                    float rden = denA[rl];
#pragma unroll
                    for (int n = 0; n < 4; n++) {
                        int col = nb + n * 16 + l15;
                        float vv = bf2f(Vmat[(size_t)rowc * HID + col]);
                        float pv = bf2f(Prev[(size_t)rowc * HID + col]);
                        float num = acc[m][n][r] + Nf * vv;
                        acc[m][n][r] = 0.5f * num * rden + 0.5f * pv;
                    }
                }
        } else {
            float bn[4];
#pragma unroll
            for (int n = 0; n < 4; n++) bn[n] = bias[nb + n * 16 + l15];
#pragma unroll
            for (int m = 0; m < 8; m++)
#pragma unroll
                for (int n = 0; n < 4; n++)
#pragma unroll
                    for (int r = 0; r < 4; r++) acc[m][n][r] += bn[n];
        }
        // row mean/var: in-lane over n, shfl over the 16 lanes of each quad
#pragma unroll
        for (int m = 0; m < 8; m++)
#pragma unroll
            for (int r = 0; r < 4; r++) {
                float s = 0.f, s2 = 0.f;
#pragma unroll
                for (int n = 0; n < 4; n++) { float x = acc[m][n][r]; s += x; s2 += x * x; }
#pragma unroll
                for (int off = 1; off < 16; off <<= 1) {
                    s += __shfl_xor(s, off);
                    s2 += __shfl_xor(s2, off);
                }
                if (l15 == 0) {
                    int rl = m * 16 + quad * 4 + r;
                    redS[rl][wave] = s;
                    redQ[rl][wave] = s2;
                }
            }
        __syncthreads();
        if (tid < TM) {
            float s = redS[tid][0] + redS[tid][1] + redS[tid][2] + redS[tid][3];
            float s2 = redQ[tid][0] + redQ[tid][1] + redQ[tid][2] + redQ[tid][3];
            float mean = s * (1.0f / 256.0f);
            float var = s2 * (1.0f / 256.0f) - mean * mean;
            rowm[tid] = mean;
            rowr[tid] = rsqrtf(var + EPSLN);
        }
        __syncthreads();
        float g[4], bb[4];
#pragma unroll
        for (int n = 0; n < 4; n++) {
            g[n] = lng[nb + n * 16 + l15];
            bb[n] = lnb[nb + n * 16 + l15];
        }
#pragma unroll
        for (int m = 0; m < 8; m++)
#pragma unroll
            for (int r = 0; r < 4; r++) {
                int rl = m * 16 + quad * 4 + r;
                int row = row0 + rl;
                if (row < M_ROWS) {
                    float mean = rowm[rl], rstd = rowr[rl];
#pragma unroll
                    for (int n = 0; n < 4; n++) {
                        float x = (acc[m][n][r] - mean) * rstd * g[n] + bb[n];
                        if constexpr (EPI == 1) x = fmaxf(x, 0.f);
                        C[(size_t)row * HID + nb + n * 16 + l15] = f2bf(x);
                    }
                }
            }
    }
}

// ---------------------------------------------------------------------------
// KV = k^T @ v  [256x256] f32, split-K over grid.z (256), LDS-transposed MFMA.
// ---------------------------------------------------------------------------
__global__ __launch_bounds__(256)
void kv_kernel(const short* __restrict__ k, const short* __restrict__ v,
               float* __restrict__ KV, int M)
{
    __shared__ short ksT[128][40];
    __shared__ short vsT[128][40];
    const int t = threadIdx.x, wave = t >> 6, lane = t & 63;
    const int quad = lane >> 4, l15 = lane & 15;
    const int mb = blockIdx.x * 128, nbb = blockIdx.y * 128;
    const int chunk = (M + (int)gridDim.z - 1) / (int)gridDim.z;
    const int rbeg = blockIdx.z * chunk;
    const int rend = min(M, rbeg + chunk);

    floatx4 acc[2][8];
#pragma unroll
    for (int m = 0; m < 2; m++)
#pragma unroll
        for (int j = 0; j < 8; j++) acc[m][j] = (floatx4)0.0f;

    const int lr = t >> 3, c0 = (t & 7) * 16;
    const int wm = wave * 32;

    for (int r0 = rbeg; r0 < rend; r0 += 32) {
        int gr = r0 + lr;
        short8 k0 = (short8)(short)0, k1 = (short8)(short)0;
        short8 v0 = (short8)(short)0, v1 = (short8)(short)0;
        if (gr < rend) {
            const short* kp = k + (size_t)gr * HID + mb + c0;
            const short* vp = v + (size_t)gr * HID + nbb + c0;
            k0 = *(const short8*)kp;  k1 = *(const short8*)(kp + 8);
            v0 = *(const short8*)vp;  v1 = *(const short8*)(vp + 8);
        }
        __syncthreads();
#pragma unroll
        for (int i = 0; i < 8; i++) {
            ksT[c0 + i][lr] = k0[i];  ksT[c0 + 8 + i][lr] = k1[i];
            vsT[c0 + i][lr] = v0[i];  vsT[c0 + 8 + i][lr] = v1[i];
        }
        __syncthreads();
        short8 a0 = *(const short8*)&ksT[wm + l15][quad * 8];
        short8 a1 = *(const short8*)&ksT[wm + 16 + l15][quad * 8];
#pragma unroll
        for (int j = 0; j < 8; j++) {
            short8 b = *(const short8*)&vsT[j * 16 + l15][quad * 8];
            acc[0][j] = __builtin_amdgcn_mfma_f32_16x16x32_bf16(a0, b, acc[0][j], 0, 0, 0);
            acc[1][j] = __builtin_amdgcn_mfma_f32_16x16x32_bf16(a1, b, acc[1][j], 0, 0, 0);
        }
    }
#pragma unroll
    for (int mi = 0; mi < 2; mi++)
#pragma unroll
        for (int j = 0; j < 8; j++)
#pragma unroll
            for (int r = 0; r < 4; r++) {
                int m = mb + wm + mi * 16 + quad * 4 + r;
                int n = nbb + j * 16 + l15;
                atomicAdd(&KV[(size_t)m * HID + n], acc[mi][j][r]);
            }
}

// KVt[272][256]: rows 0..255 = (KV*s)^T bf16, row 256 = ksum*s, 257..271 = 0
__global__ void scale_kernel(const float* __restrict__ KV, const float* __restrict__ ksum,
                             const float* __restrict__ sq, short* __restrict__ KVt)
{
    float s = rsqrtf(sq[0]) * rsqrtf(sq[1]);
    int d = blockIdx.x;   // 0..271
    int m = threadIdx.x;  // 0..255
    float val;
    if (d < 256)       val = KV[(size_t)m * HID + d] * s;
    else if (d == 256) val = ksum[m] * s;
    else               val = 0.f;
    KVt[(size_t)d * HID + m] = f2bf(val);
}

// ---------------------------------------------------------------------------
// Final GEMM: Out[M,40] = h[M,256] @ W_out[256,40] + b_out (N padded to 48)
// ---------------------------------------------------------------------------
__global__ __launch_bounds__(256)
void gemm_out(const short* __restrict__ A, const short* __restrict__ BT,
              const float* __restrict__ bias, float* __restrict__ Out, int M)
{
    const int tid = threadIdx.x, wave = tid >> 6, lane = tid & 63;
    const int quad = lane >> 4, l15 = lane & 15;
    const int row0 = blockIdx.x * 128 + wave * 32;
    const int K = 256;
    floatx4 acc[2][3];
#pragma unroll
    for (int m = 0; m < 2; m++)
#pragma unroll
        for (int n = 0; n < 3; n++) acc[m][n] = (floatx4)0.0f;

    int ra0 = min(row0 + l15, M - 1);
    int ra1 = min(row0 + 16 + l15, M - 1);
    for (int kk = 0; kk < K; kk += 32) {
        short8 a0 = *(const short8*)(A + (size_t)ra0 * K + kk + quad * 8);
        short8 a1 = *(const short8*)(A + (size_t)ra1 * K + kk + quad * 8);
#pragma unroll
        for (int n = 0; n < 3; n++) {
            int col = n * 16 + l15;
            short8 b = (short8)(short)0;
            if (col < 40) b = *(const short8*)(BT + (size_t)col * K + kk + quad * 8);
            acc[0][n] = __builtin_amdgcn_mfma_f32_16x16x32_bf16(a0, b, acc[0][n], 0, 0, 0);
            acc[1][n] = __builtin_amdgcn_mfma_f32_16x16x32_bf16(a1, b, acc[1][n], 0, 0, 0);
        }
    }
#pragma unroll
    for (int m = 0; m < 2; m++)
#pragma unroll
        for (int n = 0; n < 3; n++)
#pragma unroll
            for (int r = 0; r < 4; r++) {
                int row = row0 + m * 16 + quad * 4 + r;
                int col = n * 16 + l15;
                if (row < M && col < 40)
                    Out[(size_t)row * 40 + col] = acc[m][n][r] + bias[col];
            }
}

// --------------------------- small utility kernels -------------------------
struct TJobs { const float* src[8]; short* dst[8]; int R[8]; int C[8]; };

__global__ void wtrans(TJobs j)  // dst[C][R] = bf16(src[R][C])
{
    int job = blockIdx.y;
    int R = j.R[job], Cc = j.C[job];
    const float* s = j.src[job];
    short* d = j.dst[job];
    int n = R * Cc;
    for (int idx = blockIdx.x * 256 + threadIdx.x; idx < n; idx += gridDim.x * 256) {
        int r = idx / Cc, c = idx - r * Cc;
        d[(size_t)c * R + r] = f2bf(s[idx]);
    }
}

__global__ void zerof(float* p, int n)
{
    int i = blockIdx.x * 256 + threadIdx.x;
    if (i < n) p[i] = 0.f;
}

// ---------------------------------------------------------------------------
extern "C" void kernel_launch(void* const* d_in, const int* in_sizes, int n_in,
                              void* d_out, int out_size, void* d_ws, size_t ws_size,
                              hipStream_t stream)
{
    const float* x    = (const float*)d_in[0];
    // d_in[1] = edge_index: unused (use_graph=False)
    const float* W_in = (const float*)d_in[2];
    const float* b_in = (const float*)d_in[3];
    const float* ln0g = (const float*)d_in[4];
    const float* ln0b = (const float*)d_in[5];
    const float* Wq0  = (const float*)d_in[6];  const float* bq0 = (const float*)d_in[7];
    const float* Wk0  = (const float*)d_in[8];  const float* bk0 = (const float*)d_in[9];
    const float* Wv0  = (const float*)d_in[10]; const float* bv0 = (const float*)d_in[11];
    const float* ln1g = (const float*)d_in[12]; const float* ln1b = (const float*)d_in[13];
    const float* Wq1  = (const float*)d_in[14]; const float* bq1 = (const float*)d_in[15];
    const float* Wk1  = (const float*)d_in[16]; const float* bk1 = (const float*)d_in[17];
    const float* Wv1  = (const float*)d_in[18]; const float* bv1 = (const float*)d_in[19];
    const float* ln2g = (const float*)d_in[20]; const float* ln2b = (const float*)d_in[21];
    const float* W_out = (const float*)d_in[22]; const float* b_out = (const float*)d_in[23];

    const int M = M_ROWS;
    char* ws = (char*)d_ws;
    size_t off = 0;
    auto alloc = [&](size_t bytes) -> char* {
        char* p = ws + off;
        off += (bytes + 255) & ~(size_t)255;
        return p;
    };
    short* h = (short*)alloc((size_t)M * HID * 2);
    short* q = (short*)alloc((size_t)M * HID * 2);
    short* k = (short*)alloc((size_t)M * HID * 2);
    short* v = (short*)alloc((size_t)M * HID * 2);
    short* WinT  = (short*)alloc((size_t)512 * 256 * 2);
    short* WqT0  = (short*)alloc((size_t)65536 * 2);
    short* WkT0  = (short*)alloc((size_t)65536 * 2);
    short* WvT0  = (short*)alloc((size_t)65536 * 2);
    short* WqT1  = (short*)alloc((size_t)65536 * 2);
    short* WkT1  = (short*)alloc((size_t)65536 * 2);
    short* WvT1  = (short*)alloc((size_t)65536 * 2);
    short* WoutT = (short*)alloc((size_t)40 * 256 * 2);
    float* zbase = (float*)alloc((size_t)(65536 * 2 + 256 * 2 + 4) * 4);
    float* KV0 = zbase;
    float* KV1 = zbase + 65536;
    float* ksum0 = zbase + 131072;
    float* ksum1 = ksum0 + 256;
    float* sq = ksum1 + 256;  // [sq_q0, sq_k0, sq_q1, sq_k1]
    short* KVt0 = (short*)alloc((size_t)272 * 256 * 2);
    short* KVt1 = (short*)alloc((size_t)272 * 256 * 2);

    const int ZN = 65536 * 2 + 256 * 2 + 4;
    zerof<<<dim3((ZN + 255) / 256), 256, 0, stream>>>(zbase, ZN);

    TJobs tj;
    tj.src[0] = W_in;  tj.dst[0] = WinT;  tj.R[0] = 512; tj.C[0] = 256;
    tj.src[1] = Wq0;   tj.dst[1] = WqT0;  tj.R[1] = 256; tj.C[1] = 256;
    tj.src[2] = Wk0;   tj.dst[2] = WkT0;  tj.R[2] = 256; tj.C[2] = 256;
    tj.src[3] = Wv0;   tj.dst[3] = WvT0;  tj.R[3] = 256; tj.C[3] = 256;
    tj.src[4] = Wq1;   tj.dst[4] = WqT1;  tj.R[4] = 256; tj.C[4] = 256;
    tj.src[5] = Wk1;   tj.dst[5] = WkT1;  tj.R[5] = 256; tj.C[5] = 256;
    tj.src[6] = Wv1;   tj.dst[6] = WvT1;  tj.R[6] = 256; tj.C[6] = 256;
    tj.src[7] = W_out; tj.dst[7] = WoutT; tj.R[7] = 256; tj.C[7] = 40;
    wtrans<<<dim3(512, 8), 256, 0, stream>>>(tj);

    const int GB = (M + TM - 1) / TM;  // 782
    const float Nf = (float)M;

    // stage 0: h = relu(LN(x @ W_in + b_in))   (x f32, converted inline)
    gemm_panel<1, true><<<GB, 256, 0, stream>>>(x, WinT, h, 512, b_in,
                                          nullptr, nullptr, ln0g, ln0b,
                                          nullptr, nullptr, 0.f);
    // ---- layer 0 ----
    gemm_panel<0, false><<<GB, 256, 0, stream>>>(h, WqT0, q, 256, bq0, sq + 0, nullptr,
                                          nullptr, nullptr, nullptr, nullptr, 0.f);
    gemm_panel<0, false><<<GB, 256, 0, stream>>>(h, WkT0, k, 256, bk0, sq + 1, ksum0,
                                          nullptr, nullptr, nullptr, nullptr, 0.f);
    gemm_panel<0, false><<<GB, 256, 0, stream>>>(h, WvT0, v, 256, bv0, nullptr, nullptr,
                                          nullptr, nullptr, nullptr, nullptr, 0.f);
    kv_kernel<<<dim3(2, 2, 256), 256, 0, stream>>>(k, v, KV0, M);
    scale_kernel<<<272, 256, 0, stream>>>(KV0, ksum0, sq + 0, KVt0);
    gemm_panel<2, false><<<GB, 256, 0, stream>>>(q, KVt0, h, 256, nullptr,
                                          nullptr, nullptr, ln1g, ln1b,
                                          v, h, Nf);
    // ---- layer 1 ----
    gemm_panel<0, false><<<GB, 256, 0, stream>>>(h, WqT1, q, 256, bq1, sq + 2, nullptr,
                                          nullptr, nullptr, nullptr, nullptr, 0.f);
    gemm_panel<0, false><<<GB, 256, 0, stream>>>(h, WkT1, k, 256, bk1, sq + 3, ksum1,
                                          nullptr, nullptr, nullptr, nullptr, 0.f);
    gemm_panel<0, false><<<GB, 256, 0, stream>>>(h, WvT1, v, 256, bv1, nullptr, nullptr,
                                          nullptr, nullptr, nullptr, nullptr, 0.f);
    kv_kernel<<<dim3(2, 2, 256), 256, 0, stream>>>(k, v, KV1, M);
    scale_kernel<<<272, 256, 0, stream>>>(KV1, ksum1, sq + 2, KVt1);
    gemm_panel<2, false><<<GB, 256, 0, stream>>>(q, KVt1, h, 256, nullptr,
                                          nullptr, nullptr, ln2g, ln2b,
                                          v, h, Nf);
    // ---- output ----
    gemm_out<<<(M + 127) / 128, 256, 0, stream>>>(h, WoutT, b_out, (float*)d_out, M);
}

// Round 4
// 1070.414 us; speedup vs baseline: 1.3590x; 1.2134x over previous
//
#include <hip/hip_runtime.h>

// ---------------------------------------------------------------------------
// SGFormer forward, MI355X/gfx950.  I/O f32; internal h/q/k/v bf16.
// attn = (q @ (k^T v) * s + N*v) / (q . (sum_k) * s + N),  s = 1/(||q|| ||k||)
// KVt[272][256]: rows 0..255 = (KV*s)^T, row 256 = ksum*s, 257..271 = 0; the
// denominator comes from one extra MFMA column (wave 0) on KVt row 256.
//
// R3 lesson: 128-row tiles -> 336 unified VGPR+AGPR/wave -> 1 wave/SIMD ->
// latency-bound (MfmaUtil 4.8%). This round: 64-row blocks, acc[4][4] (64
// AGPR), launch_bounds(256,3) -> 3 waves/SIMD; fused qkv (one A staging, 3
// GEMMs); LDS-bounce coalesced stores (kills partial-line write-allocate
// RMW that showed as FETCH ~= 2x ideal).
// ---------------------------------------------------------------------------

typedef __attribute__((ext_vector_type(8))) short short8;
typedef __attribute__((ext_vector_type(4))) float floatx4;

__device__ __forceinline__ float bf2f(short u) {
    union { unsigned int i; float f; } v;
    v.i = ((unsigned int)(unsigned short)u) << 16;
    return v.f;
}
__device__ __forceinline__ short f2bf(float f) {
    union { float f; unsigned int i; } v; v.f = f;
    unsigned int b = v.i + 0x7fffu + ((v.i >> 16) & 1u);  // RNE
    return (short)(b >> 16);
}

#define HID 256
#define MROWS 100000
#define EPSLN 1e-5f

// ---- stage a 64x256 bf16 A-tile into LDS via global_load_lds, XOR-swizzled.
// Chunk J (16B) holds row J>>5, logical chunk (J&31)^(row&31).
__device__ __forceinline__ void stage_a256(const short* __restrict__ A, short* As,
                                           int row0, int wave, int lane)
{
    const int base = wave * 512;
#pragma unroll
    for (int it = 0; it < 8; ++it) {
        int J = base + it * 64 + lane;
        int row = J >> 5, jj = J & 31;
        int c = jj ^ (row & 31);
        int rowg = min(row0 + row, MROWS - 1);
        const short* gp = A + (size_t)rowg * HID + c * 8;
        __builtin_amdgcn_global_load_lds(
            (const __attribute__((address_space(1))) void*)gp,
            (__attribute__((address_space(3))) void*)&As[(size_t)(base + it * 64) * 8],
            16, 0, 0);
    }
}
__device__ __forceinline__ short8 read_a256(const short* As, int m, int ki, int quad, int l15)
{
    int row = m * 16 + l15;
    int phys = (ki * 4 + quad) ^ (row & 31);
    return *(const short8*)&As[((size_t)row * 32 + phys) * 8];
}

// ---------------------------------------------------------------------------
// Fused q/k/v projection: one 64x256 h-tile staged once, 3 GEMMs off it.
// Also: Frobenius sumsq for q and k, column-sum for k.
// ---------------------------------------------------------------------------
__global__ __launch_bounds__(256, 3)
void qkv_kernel(const short* __restrict__ h,
                const short* __restrict__ BTq, const short* __restrict__ BTk,
                const short* __restrict__ BTv,
                const float* __restrict__ bq, const float* __restrict__ bk,
                const float* __restrict__ bv,
                short* __restrict__ qO, short* __restrict__ kO, short* __restrict__ vO,
                float* __restrict__ sqq, float* __restrict__ sqk,
                float* __restrict__ ksum)
{
    __shared__ short As[64 * 256];      // 32 KB
    __shared__ short Cb[16 * 264];      // 8.25 KB bounce
    __shared__ float scr;

    const int tid = threadIdx.x, wave = tid >> 6, lane = tid & 63;
    const int quad = lane >> 4, l15 = lane & 15;
    const int row0 = blockIdx.x * 64, nb = wave * 64;

    stage_a256(h, As, row0, wave, lane);
    __syncthreads();

    const short* BTs[3] = {BTq, BTk, BTv};
    short* Cs[3] = {qO, kO, vO};
    const float* bs[3] = {bq, bk, bv};

#pragma unroll
    for (int out = 0; out < 3; ++out) {
        const short* BT = BTs[out];
        short* C = Cs[out];
        const float* bias = bs[out];

        floatx4 acc[4][4];
#pragma unroll
        for (int m = 0; m < 4; m++)
#pragma unroll
            for (int n = 0; n < 4; n++) acc[m][n] = (floatx4)0.0f;

#pragma unroll
        for (int ki = 0; ki < 8; ++ki) {
            short8 a[4];
#pragma unroll
            for (int m = 0; m < 4; ++m) a[m] = read_a256(As, m, ki, quad, l15);
#pragma unroll
            for (int n = 0; n < 4; ++n) {
                short8 b = *(const short8*)(BT + (size_t)(nb + n * 16 + l15) * 256 + ki * 32 + quad * 8);
#pragma unroll
                for (int m = 0; m < 4; ++m)
                    acc[m][n] = __builtin_amdgcn_mfma_f32_16x16x32_bf16(a[m], b, acc[m][n], 0, 0, 0);
            }
        }

        float bn[4];
#pragma unroll
        for (int n = 0; n < 4; n++) bn[n] = bias[nb + n * 16 + l15];

        float ssq = 0.f;
        float csum[4] = {0.f, 0.f, 0.f, 0.f};
#pragma unroll
        for (int m = 0; m < 4; m++)
#pragma unroll
            for (int r = 0; r < 4; r++) {
                int rl = m * 16 + quad * 4 + r;
                bool valid = (row0 + rl) < MROWS;
#pragma unroll
                for (int n = 0; n < 4; n++) {
                    float val = acc[m][n][r] + bn[n];
                    acc[m][n][r] = val;
                    if (valid) {
                        if (out < 2) ssq += val * val;
                        if (out == 1) csum[n] += val;
                    }
                }
            }
        if (out < 2) {
#pragma unroll
            for (int off = 32; off; off >>= 1) ssq += __shfl_down(ssq, off);
            if (tid == 0) scr = 0.f;
            __syncthreads();
            if (lane == 0) atomicAdd(&scr, ssq);
            __syncthreads();
            if (tid == 0) atomicAdd(out == 0 ? sqq : sqk, scr);
        }
        if (out == 1) {
#pragma unroll
            for (int n = 0; n < 4; n++) {
                float cv = csum[n];
                cv += __shfl_xor(cv, 16);
                cv += __shfl_xor(cv, 32);
                if (quad == 0) atomicAdd(&ksum[nb + n * 16 + l15], cv);
            }
        }
        // coalesced store via bounce: 16-row stripes
#pragma unroll
        for (int m = 0; m < 4; ++m) {
            __syncthreads();
#pragma unroll
            for (int n = 0; n < 4; ++n)
#pragma unroll
                for (int r = 0; r < 4; ++r)
                    Cb[(quad * 4 + r) * 264 + nb + n * 16 + l15] = f2bf(acc[m][n][r]);
            __syncthreads();
#pragma unroll
            for (int ch = tid; ch < 512; ch += 256) {
                int rl = ch >> 5, co = (ch & 31) * 8;
                int row = row0 + m * 16 + rl;
                if (row < MROWS)
                    *(short8*)(C + (size_t)row * 256 + co) = *(const short8*)&Cb[rl * 264 + co];
            }
        }
    }
}

// ---------------------------------------------------------------------------
// Attention epilogue GEMM: acc = q @ KVt_s (den col = KVt row 256, wave 0);
// h = 0.5*(acc + N*v)/den + 0.5*h; LayerNorm; in-place (own 64 rows only).
// ---------------------------------------------------------------------------
__global__ __launch_bounds__(256, 3)
void attn_kernel(const short* __restrict__ q, const short* __restrict__ KVt,
                 const short* __restrict__ v, short* __restrict__ h,
                 const float* __restrict__ lng, const float* __restrict__ lnb,
                 float Nf)
{
    __shared__ short As[64 * 256];
    __shared__ short Cb[16 * 264];
    __shared__ float redS[64][4], redQ[64][4];
    __shared__ float rowm[64], rowr[64], denA[64];

    const int tid = threadIdx.x, wave = tid >> 6, lane = tid & 63;
    const int quad = lane >> 4, l15 = lane & 15;
    const int row0 = blockIdx.x * 64, nb = wave * 64;

    stage_a256(q, As, row0, wave, lane);
    __syncthreads();

    floatx4 acc[4][4];
#pragma unroll
    for (int m = 0; m < 4; m++)
#pragma unroll
        for (int n = 0; n < 4; n++) acc[m][n] = (floatx4)0.0f;
    floatx4 accd[4];
#pragma unroll
    for (int m = 0; m < 4; m++) accd[m] = (floatx4)0.0f;

#pragma unroll
    for (int ki = 0; ki < 8; ++ki) {
        short8 a[4];
#pragma unroll
        for (int m = 0; m < 4; ++m) a[m] = read_a256(As, m, ki, quad, l15);
#pragma unroll
        for (int n = 0; n < 4; ++n) {
            short8 b = *(const short8*)(KVt + (size_t)(nb + n * 16 + l15) * 256 + ki * 32 + quad * 8);
#pragma unroll
            for (int m = 0; m < 4; ++m)
                acc[m][n] = __builtin_amdgcn_mfma_f32_16x16x32_bf16(a[m], b, acc[m][n], 0, 0, 0);
        }
        if (wave == 0) {
            short8 bd = *(const short8*)(KVt + (size_t)(256 + l15) * 256 + ki * 32 + quad * 8);
#pragma unroll
            for (int m = 0; m < 4; ++m)
                accd[m] = __builtin_amdgcn_mfma_f32_16x16x32_bf16(a[m], bd, accd[m], 0, 0, 0);
        }
    }
    if (wave == 0 && l15 == 0) {
#pragma unroll
        for (int m = 0; m < 4; m++)
#pragma unroll
            for (int r = 0; r < 4; r++)
                denA[m * 16 + quad * 4 + r] = accd[m][r];
    }
    __syncthreads();

    // fold v/prev + LN stats
#pragma unroll
    for (int m = 0; m < 4; m++)
#pragma unroll
        for (int r = 0; r < 4; r++) {
            int rl = m * 16 + quad * 4 + r;
            int rowc = min(row0 + rl, MROWS - 1);
            float rden = 1.0f / (denA[rl] + Nf);
            float s = 0.f, s2 = 0.f;
#pragma unroll
            for (int n = 0; n < 4; n++) {
                int col = nb + n * 16 + l15;
                float vv = bf2f(v[(size_t)rowc * 256 + col]);
                float pv = bf2f(h[(size_t)rowc * 256 + col]);
                float val = 0.5f * (acc[m][n][r] + Nf * vv) * rden + 0.5f * pv;
                acc[m][n][r] = val;
                s += val; s2 += val * val;
            }
#pragma unroll
            for (int off = 1; off < 16; off <<= 1) {
                s += __shfl_xor(s, off);
                s2 += __shfl_xor(s2, off);
            }
            if (l15 == 0) { redS[rl][wave] = s; redQ[rl][wave] = s2; }
        }
    __syncthreads();
    if (tid < 64) {
        float s = redS[tid][0] + redS[tid][1] + redS[tid][2] + redS[tid][3];
        float s2 = redQ[tid][0] + redQ[tid][1] + redQ[tid][2] + redQ[tid][3];
        float mean = s * (1.0f / 256.0f);
        float var = s2 * (1.0f / 256.0f) - mean * mean;
        rowm[tid] = mean;
        rowr[tid] = rsqrtf(var + EPSLN);
    }
    __syncthreads();
    float g[4], bb[4];
#pragma unroll
    for (int n = 0; n < 4; n++) {
        g[n] = lng[nb + n * 16 + l15];
        bb[n] = lnb[nb + n * 16 + l15];
    }
#pragma unroll
    for (int m = 0; m < 4; ++m) {
        __syncthreads();
#pragma unroll
        for (int n = 0; n < 4; ++n)
#pragma unroll
            for (int r = 0; r < 4; ++r) {
                int rl = m * 16 + quad * 4 + r;
                float x = (acc[m][n][r] - rowm[rl]) * rowr[rl] * g[n] + bb[n];
                Cb[(quad * 4 + r) * 264 + nb + n * 16 + l15] = f2bf(x);
            }
        __syncthreads();
#pragma unroll
        for (int ch = tid; ch < 512; ch += 256) {
            int rl = ch >> 5, co = (ch & 31) * 8;
            int row = row0 + m * 16 + rl;
            if (row < MROWS)
                *(short8*)(h + (size_t)row * 256 + co) = *(const short8*)&Cb[rl * 264 + co];
        }
    }
}

// ---------------------------------------------------------------------------
// Stage 0: h = relu(LN(x @ W_in + b_in)); x f32, K=512, slabbed KTILE=128.
// ---------------------------------------------------------------------------
__global__ __launch_bounds__(256, 3)
void in_kernel(const float* __restrict__ x, const short* __restrict__ WinT,
               const float* __restrict__ b_in, const float* __restrict__ lng,
               const float* __restrict__ lnb, short* __restrict__ h)
{
    __shared__ short As[64 * 128];      // 16 KB
    __shared__ short Cb[16 * 264];
    __shared__ float redS[64][4], redQ[64][4];
    __shared__ float rowm[64], rowr[64];

    const int tid = threadIdx.x, wave = tid >> 6, lane = tid & 63;
    const int quad = lane >> 4, l15 = lane & 15;
    const int row0 = blockIdx.x * 64, nb = wave * 64;

    floatx4 acc[4][4];
#pragma unroll
    for (int m = 0; m < 4; m++)
#pragma unroll
        for (int n = 0; n < 4; n++) acc[m][n] = (floatx4)0.0f;

    for (int slab = 0; slab < 512; slab += 128) {
        __syncthreads();
#pragma unroll
        for (int it = 0; it < 4; ++it) {
            int J = it * 256 + tid;
            int row = J >> 4, jj = J & 15, c = jj ^ (row & 15);
            int rowg = min(row0 + row, MROWS - 1);
            const float* gp = x + (size_t)rowg * 512 + slab + c * 8;
            floatx4 x0 = *(const floatx4*)gp;
            floatx4 x1 = *(const floatx4*)(gp + 4);
            short8 s8;
#pragma unroll
            for (int i = 0; i < 4; ++i) { s8[i] = f2bf(x0[i]); s8[i + 4] = f2bf(x1[i]); }
            *(short8*)&As[(size_t)J * 8] = s8;
        }
        __syncthreads();
#pragma unroll
        for (int ki = 0; ki < 4; ++ki) {
            short8 a[4];
#pragma unroll
            for (int m = 0; m < 4; ++m) {
                int row = m * 16 + l15;
                int phys = (ki * 4 + quad) ^ (row & 15);
                a[m] = *(const short8*)&As[((size_t)row * 16 + phys) * 8];
            }
#pragma unroll
            for (int n = 0; n < 4; ++n) {
                short8 b = *(const short8*)(WinT + (size_t)(nb + n * 16 + l15) * 512 + slab + ki * 32 + quad * 8);
#pragma unroll
                for (int m = 0; m < 4; ++m)
                    acc[m][n] = __builtin_amdgcn_mfma_f32_16x16x32_bf16(a[m], b, acc[m][n], 0, 0, 0);
            }
        }
    }
    // bias + LN stats
    float bn[4];
#pragma unroll
    for (int n = 0; n < 4; n++) bn[n] = b_in[nb + n * 16 + l15];
#pragma unroll
    for (int m = 0; m < 4; m++)
#pragma unroll
        for (int r = 0; r < 4; r++) {
            int rl = m * 16 + quad * 4 + r;
            float s = 0.f, s2 = 0.f;
#pragma unroll
            for (int n = 0; n < 4; n++) {
                float val = acc[m][n][r] + bn[n];
                acc[m][n][r] = val;
                s += val; s2 += val * val;
            }
#pragma unroll
            for (int off = 1; off < 16; off <<= 1) {
                s += __shfl_xor(s, off);
                s2 += __shfl_xor(s2, off);
            }
            if (l15 == 0) { redS[rl][wave] = s; redQ[rl][wave] = s2; }
        }
    __syncthreads();
    if (tid < 64) {
        float s = redS[tid][0] + redS[tid][1] + redS[tid][2] + redS[tid][3];
        float s2 = redQ[tid][0] + redQ[tid][1] + redQ[tid][2] + redQ[tid][3];
        float mean = s * (1.0f / 256.0f);
        float var = s2 * (1.0f / 256.0f) - mean * mean;
        rowm[tid] = mean;
        rowr[tid] = rsqrtf(var + EPSLN);
    }
    __syncthreads();
    float g[4], bb[4];
#pragma unroll
    for (int n = 0; n < 4; n++) {
        g[n] = lng[nb + n * 16 + l15];
        bb[n] = lnb[nb + n * 16 + l15];
    }
#pragma unroll
    for (int m = 0; m < 4; ++m) {
        __syncthreads();
#pragma unroll
        for (int n = 0; n < 4; ++n)
#pragma unroll
            for (int r = 0; r < 4; ++r) {
                int rl = m * 16 + quad * 4 + r;
                float xv = (acc[m][n][r] - rowm[rl]) * rowr[rl] * g[n] + bb[n];
                Cb[(quad * 4 + r) * 264 + nb + n * 16 + l15] = f2bf(fmaxf(xv, 0.f));
            }
        __syncthreads();
#pragma unroll
        for (int ch = tid; ch < 512; ch += 256) {
            int rl = ch >> 5, co = (ch & 31) * 8;
            int row = row0 + m * 16 + rl;
            if (row < MROWS)
                *(short8*)(h + (size_t)row * 256 + co) = *(const short8*)&Cb[rl * 264 + co];
        }
    }
}

// ---------------------------------------------------------------------------
// KV = k^T @ v  [256x256] f32, split-K over grid.z (256), LDS-transposed MFMA.
// ---------------------------------------------------------------------------
__global__ __launch_bounds__(256)
void kv_kernel(const short* __restrict__ k, const short* __restrict__ v,
               float* __restrict__ KV, int M)
{
    __shared__ short ksT[128][40];
    __shared__ short vsT[128][40];
    const int t = threadIdx.x, wave = t >> 6, lane = t & 63;
    const int quad = lane >> 4, l15 = lane & 15;
    const int mb = blockIdx.x * 128, nbb = blockIdx.y * 128;
    const int chunk = (M + (int)gridDim.z - 1) / (int)gridDim.z;
    const int rbeg = blockIdx.z * chunk;
    const int rend = min(M, rbeg + chunk);

    floatx4 acc[2][8];
#pragma unroll
    for (int m = 0; m < 2; m++)
#pragma unroll
        for (int j = 0; j < 8; j++) acc[m][j] = (floatx4)0.0f;

    const int lr = t >> 3, c0 = (t & 7) * 16;
    const int wm = wave * 32;

    for (int r0 = rbeg; r0 < rend; r0 += 32) {
        int gr = r0 + lr;
        short8 k0 = (short8)(short)0, k1 = (short8)(short)0;
        short8 v0 = (short8)(short)0, v1 = (short8)(short)0;
        if (gr < rend) {
            const short* kp = k + (size_t)gr * HID + mb + c0;
            const short* vp = v + (size_t)gr * HID + nbb + c0;
            k0 = *(const short8*)kp;  k1 = *(const short8*)(kp + 8);
            v0 = *(const short8*)vp;  v1 = *(const short8*)(vp + 8);
        }
        __syncthreads();
#pragma unroll
        for (int i = 0; i < 8; i++) {
            ksT[c0 + i][lr] = k0[i];  ksT[c0 + 8 + i][lr] = k1[i];
            vsT[c0 + i][lr] = v0[i];  vsT[c0 + 8 + i][lr] = v1[i];
        }
        __syncthreads();
        short8 a0 = *(const short8*)&ksT[wm + l15][quad * 8];
        short8 a1 = *(const short8*)&ksT[wm + 16 + l15][quad * 8];
#pragma unroll
        for (int j = 0; j < 8; j++) {
            short8 b = *(const short8*)&vsT[j * 16 + l15][quad * 8];
            acc[0][j] = __builtin_amdgcn_mfma_f32_16x16x32_bf16(a0, b, acc[0][j], 0, 0, 0);
            acc[1][j] = __builtin_amdgcn_mfma_f32_16x16x32_bf16(a1, b, acc[1][j], 0, 0, 0);
        }
    }
#pragma unroll
    for (int mi = 0; mi < 2; mi++)
#pragma unroll
        for (int j = 0; j < 8; j++)
#pragma unroll
            for (int r = 0; r < 4; r++) {
                int m = mb + wm + mi * 16 + quad * 4 + r;
                int n = nbb + j * 16 + l15;
                atomicAdd(&KV[(size_t)m * HID + n], acc[mi][j][r]);
            }
}

// KVt[272][256]: rows 0..255 = (KV*s)^T bf16, row 256 = ksum*s, 257..271 = 0
__global__ void scale_kernel(const float* __restrict__ KV, const float* __restrict__ ksum,
                             const float* __restrict__ sq, short* __restrict__ KVt)
{
    float s = rsqrtf(sq[0]) * rsqrtf(sq[1]);
    int d = blockIdx.x;   // 0..271
    int m = threadIdx.x;  // 0..255
    float val;
    if (d < 256)       val = KV[(size_t)m * HID + d] * s;
    else if (d == 256) val = ksum[m] * s;
    else               val = 0.f;
    KVt[(size_t)d * HID + m] = f2bf(val);
}

// ---------------------------------------------------------------------------
// Final GEMM: Out[M,40] = h[M,256] @ W_out[256,40] + b_out (N padded to 48)
// ---------------------------------------------------------------------------
__global__ __launch_bounds__(256)
void gemm_out(const short* __restrict__ A, const short* __restrict__ BT,
              const float* __restrict__ bias, float* __restrict__ Out, int M)
{
    const int tid = threadIdx.x, wave = tid >> 6, lane = tid & 63;
    const int quad = lane >> 4, l15 = lane & 15;
    const int row0 = blockIdx.x * 128 + wave * 32;
    const int K = 256;
    floatx4 acc[2][3];
#pragma unroll
    for (int m = 0; m < 2; m++)
#pragma unroll
        for (int n = 0; n < 3; n++) acc[m][n] = (floatx4)0.0f;

    int ra0 = min(row0 + l15, M - 1);
    int ra1 = min(row0 + 16 + l15, M - 1);
    for (int kk = 0; kk < K; kk += 32) {
        short8 a0 = *(const short8*)(A + (size_t)ra0 * K + kk + quad * 8);
        short8 a1 = *(const short8*)(A + (size_t)ra1 * K + kk + quad * 8);
#pragma unroll
        for (int n = 0; n < 3; n++) {
            int col = n * 16 + l15;
            short8 b = (short8)(short)0;
            if (col < 40) b = *(const short8*)(BT + (size_t)col * K + kk + quad * 8);
            acc[0][n] = __builtin_amdgcn_mfma_f32_16x16x32_bf16(a0, b, acc[0][n], 0, 0, 0);
            acc[1][n] = __builtin_amdgcn_mfma_f32_16x16x32_bf16(a1, b, acc[1][n], 0, 0, 0);
        }
    }
#pragma unroll
    for (int m = 0; m < 2; m++)
#pragma unroll
        for (int n = 0; n < 3; n++)
#pragma unroll
            for (int r = 0; r < 4; r++) {
                int row = row0 + m * 16 + quad * 4 + r;
                int col = n * 16 + l15;
                if (row < M && col < 40)
                    Out[(size_t)row * 40 + col] = acc[m][n][r] + bias[col];
            }
}

// --------------------------- small utility kernels -------------------------
struct TJobs { const float* src[8]; short* dst[8]; int R[8]; int C[8]; };

__global__ void wtrans(TJobs j)  // dst[C][R] = bf16(src[R][C])
{
    int job = blockIdx.y;
    int R = j.R[job], Cc = j.C[job];
    const float* s = j.src[job];
    short* d = j.dst[job];
    int n = R * Cc;
    for (int idx = blockIdx.x * 256 + threadIdx.x; idx < n; idx += gridDim.x * 256) {
        int r = idx / Cc, c = idx - r * Cc;
        d[(size_t)c * R + r] = f2bf(s[idx]);
    }
}

__global__ void zerof(float* p, int n)
{
    int i = blockIdx.x * 256 + threadIdx.x;
    if (i < n) p[i] = 0.f;
}

// ---------------------------------------------------------------------------
extern "C" void kernel_launch(void* const* d_in, const int* in_sizes, int n_in,
                              void* d_out, int out_size, void* d_ws, size_t ws_size,
                              hipStream_t stream)
{
    const float* x    = (const float*)d_in[0];
    // d_in[1] = edge_index: unused (use_graph=False)
    const float* W_in = (const float*)d_in[2];
    const float* b_in = (const float*)d_in[3];
    const float* ln0g = (const float*)d_in[4];
    const float* ln0b = (const float*)d_in[5];
    const float* Wq0  = (const float*)d_in[6];  const float* bq0 = (const float*)d_in[7];
    const float* Wk0  = (const float*)d_in[8];  const float* bk0 = (const float*)d_in[9];
    const float* Wv0  = (const float*)d_in[10]; const float* bv0 = (const float*)d_in[11];
    const float* ln1g = (const float*)d_in[12]; const float* ln1b = (const float*)d_in[13];
    const float* Wq1  = (const float*)d_in[14]; const float* bq1 = (const float*)d_in[15];
    const float* Wk1  = (const float*)d_in[16]; const float* bk1 = (const float*)d_in[17];
    const float* Wv1  = (const float*)d_in[18]; const float* bv1 = (const float*)d_in[19];
    const float* ln2g = (const float*)d_in[20]; const float* ln2b = (const float*)d_in[21];
    const float* W_out = (const float*)d_in[22]; const float* b_out = (const float*)d_in[23];

    const int M = MROWS;
    char* ws = (char*)d_ws;
    size_t off = 0;
    auto alloc = [&](size_t bytes) -> char* {
        char* p = ws + off;
        off += (bytes + 255) & ~(size_t)255;
        return p;
    };
    short* h = (short*)alloc((size_t)M * HID * 2);
    short* q = (short*)alloc((size_t)M * HID * 2);
    short* k = (short*)alloc((size_t)M * HID * 2);
    short* v = (short*)alloc((size_t)M * HID * 2);
    short* WinT  = (short*)alloc((size_t)512 * 256 * 2);
    short* WqT0  = (short*)alloc((size_t)65536 * 2);
    short* WkT0  = (short*)alloc((size_t)65536 * 2);
    short* WvT0  = (short*)alloc((size_t)65536 * 2);
    short* WqT1  = (short*)alloc((size_t)65536 * 2);
    short* WkT1  = (short*)alloc((size_t)65536 * 2);
    short* WvT1  = (short*)alloc((size_t)65536 * 2);
    short* WoutT = (short*)alloc((size_t)40 * 256 * 2);
    float* zbase = (float*)alloc((size_t)(65536 * 2 + 256 * 2 + 4) * 4);
    float* KV0 = zbase;
    float* KV1 = zbase + 65536;
    float* ksum0 = zbase + 131072;
    float* ksum1 = ksum0 + 256;
    float* sq = ksum1 + 256;  // [sq_q0, sq_k0, sq_q1, sq_k1]
    short* KVt0 = (short*)alloc((size_t)272 * 256 * 2);
    short* KVt1 = (short*)alloc((size_t)272 * 256 * 2);

    const int ZN = 65536 * 2 + 256 * 2 + 4;
    zerof<<<dim3((ZN + 255) / 256), 256, 0, stream>>>(zbase, ZN);

    TJobs tj;
    tj.src[0] = W_in;  tj.dst[0] = WinT;  tj.R[0] = 512; tj.C[0] = 256;
    tj.src[1] = Wq0;   tj.dst[1] = WqT0;  tj.R[1] = 256; tj.C[1] = 256;
    tj.src[2] = Wk0;   tj.dst[2] = WkT0;  tj.R[2] = 256; tj.C[2] = 256;
    tj.src[3] = Wv0;   tj.dst[3] = WvT0;  tj.R[3] = 256; tj.C[3] = 256;
    tj.src[4] = Wq1;   tj.dst[4] = WqT1;  tj.R[4] = 256; tj.C[4] = 256;
    tj.src[5] = Wk1;   tj.dst[5] = WkT1;  tj.R[5] = 256; tj.C[5] = 256;
    tj.src[6] = Wv1;   tj.dst[6] = WvT1;  tj.R[6] = 256; tj.C[6] = 256;
    tj.src[7] = W_out; tj.dst[7] = WoutT; tj.R[7] = 256; tj.C[7] = 40;
    wtrans<<<dim3(512, 8), 256, 0, stream>>>(tj);

    const int GB = (M + 63) / 64;  // 1563
    const float Nf = (float)M;

    in_kernel<<<GB, 256, 0, stream>>>(x, WinT, b_in, ln0g, ln0b, h);
    // ---- layer 0 ----
    qkv_kernel<<<GB, 256, 0, stream>>>(h, WqT0, WkT0, WvT0, bq0, bk0, bv0,
                                       q, k, v, sq + 0, sq + 1, ksum0);
    kv_kernel<<<dim3(2, 2, 256), 256, 0, stream>>>(k, v, KV0, M);
    scale_kernel<<<272, 256, 0, stream>>>(KV0, ksum0, sq + 0, KVt0);
    attn_kernel<<<GB, 256, 0, stream>>>(q, KVt0, v, h, ln1g, ln1b, Nf);
    // ---- layer 1 ----
    qkv_kernel<<<GB, 256, 0, stream>>>(h, WqT1, WkT1, WvT1, bq1, bk1, bv1,
                                       q, k, v, sq + 2, sq + 3, ksum1);
    kv_kernel<<<dim3(2, 2, 256), 256, 0, stream>>>(k, v, KV1, M);
    scale_kernel<<<272, 256, 0, stream>>>(KV1, ksum1, sq + 2, KVt1);
    attn_kernel<<<GB, 256, 0, stream>>>(q, KVt1, v, h, ln2g, ln2b, Nf);
    // ---- output ----
    gemm_out<<<(M + 127) / 128, 256, 0, stream>>>(h, WoutT, b_out, (float*)d_out, M);
}